// Round 2
// baseline (1182.276 us; speedup 1.0000x reference)
//
#include <hip/hip_runtime.h>
#include <math.h>
#include <stdint.h>

#define HIDDEN 4096
#define NEXP   64
#define TOKS   64                  // tokens per workgroup
#define NWAVE  8
#define KPW    (HIDDEN / NWAVE)    // 512: K-slice per wave (K-split, no main-loop barriers)
#define KC     16                  // K per staged chunk
#define NCH    (KPW / KC)          // 32 chunks per wave
#define LSTR   20                  // LDS row stride in words (16 data + 4 pad -> bank spread)
#define WV_LDS (2 * TOKS * LSTR)   // per-wave LDS floats (X tile then W tile)
#define TSTR   68                  // epilogue tile row stride (4-aligned, 2-way banks)
#define TILE_F (TOKS * TSTR)

// Fused MoE router as a register-tiled fp32 GEMM (no fp32 MFMA on CDNA4).
// WG = 512 thr = 8 waves, owns 64 tokens. Wave w owns k in [512w, 512w+512).
// Lane (tr=lane>>3, ec=lane&7) accumulates an 8-token x 8-expert tile:
// per k4-step, 16 broadcast ds_read_b128 feed 256 FMAs (8x operand reuse).
// Per-wave private LDS chunk staging => ZERO barriers in the main loop;
// one 3-round LDS tree-reduction at the end combines the 8 K-partials.
__global__ __launch_bounds__(512, 2) void router_kernel(
    const float* __restrict__ X,
    const float* __restrict__ W,
    const float* __restrict__ Bv,
    float* __restrict__ out, int nTok)
{
    __shared__ float smem[NWAVE * WV_LDS];   // 80 KiB; reused by epilogue (needs 68 KiB)

    const int tid  = threadIdx.x;
    const int lane = tid & 63;
    const int wv   = __builtin_amdgcn_readfirstlane(tid >> 6);
    const int t0   = blockIdx.x * TOKS;
    const int tr   = lane >> 3;      // token-group 0..7
    const int ec   = lane & 7;       // expert-group 0..7
    const int kw0  = wv * KPW;

    float* xlds = &smem[wv * WV_LDS];
    float* wlds = xlds + TOKS * LSTR;

    // staging mapping: round r stages rows r*16+q (q=lane>>2), lane&3 picks the float4.
    const int q   = lane >> 2;
    const int ldJ = lane & 3;

    // swizzled LDS write word-offsets (row*LSTR + (4*ldJ ^ ((row>>3)&3)<<2))
    int woff[4];
#pragma unroll
    for (int r = 0; r < 4; ++r) {
        const int row = r * 16 + q;
        woff[r] = row * LSTR + ((4 * ldJ) ^ (((row >> 3) & 3) << 2));
    }

    const float* Xg = X + (size_t)t0 * HIDDEN + kw0 + 4 * ldJ;
    const float* Wg = W + kw0 + 4 * ldJ;

    float acc[8][8];
#pragma unroll
    for (int i = 0; i < 8; ++i)
#pragma unroll
        for (int j = 0; j < 8; ++j) acc[i][j] = 0.0f;

    // prologue: stage chunk 0
    float4 gx[4], gw[4];
#pragma unroll
    for (int r = 0; r < 4; ++r) {
        gx[r] = *(const float4*)(Xg + (size_t)(r * 16 + q) * HIDDEN);
        gw[r] = *(const float4*)(Wg + (size_t)(r * 16 + q) * HIDDEN);
    }
#pragma unroll
    for (int r = 0; r < 4; ++r) {
        *(float4*)&xlds[woff[r]] = gx[r];
        *(float4*)&wlds[woff[r]] = gw[r];
    }

    const int swzX = (tr & 3) << 2;
    const int swzW = (ec & 3) << 2;

    for (int c = 0; c < NCH; ++c) {
        // T14: issue next chunk's global loads early; ~2000 cyc of FMA hides HBM.
        if (c + 1 < NCH) {
#pragma unroll
            for (int r = 0; r < 4; ++r) {
                gx[r] = *(const float4*)(Xg + (size_t)(r * 16 + q) * HIDDEN + (c + 1) * KC);
                gw[r] = *(const float4*)(Wg + (size_t)(r * 16 + q) * HIDDEN + (c + 1) * KC);
            }
        }
#pragma unroll
        for (int s = 0; s < 4; ++s) {
            float4 wf[8];
#pragma unroll
            for (int j = 0; j < 8; ++j)
                wf[j] = *(const float4*)&wlds[(8 * ec + j) * LSTR + ((4 * s) ^ swzW)];
#pragma unroll
            for (int i = 0; i < 8; ++i) {
                float4 xf = *(const float4*)&xlds[(8 * tr + i) * LSTR + ((4 * s) ^ swzX)];
#pragma unroll
                for (int j = 0; j < 8; ++j) {
                    acc[i][j] = fmaf(xf.x, wf[j].x, acc[i][j]);
                    acc[i][j] = fmaf(xf.y, wf[j].y, acc[i][j]);
                    acc[i][j] = fmaf(xf.z, wf[j].z, acc[i][j]);
                    acc[i][j] = fmaf(xf.w, wf[j].w, acc[i][j]);
                }
            }
        }
        if (c + 1 < NCH) {
            // single-buffered per-wave region: program order + lgkmcnt gives WAR safety
#pragma unroll
            for (int r = 0; r < 4; ++r) {
                *(float4*)&xlds[woff[r]] = gx[r];
                *(float4*)&wlds[woff[r]] = gw[r];
            }
        }
    }

    // ---- cross-wave K-reduction: 3 rounds of pairwise LDS adds ----
    __syncthreads();
#pragma unroll
    for (int half = 4; half >= 1; half >>= 1) {
        if (wv >= half && wv < 2 * half) {
            float* tb = &smem[(wv - half) * TILE_F];
#pragma unroll
            for (int i = 0; i < 8; ++i) {
                float* rowp = &tb[(8 * tr + i) * TSTR + 8 * ec];
                *(float4*)rowp       = make_float4(acc[i][0], acc[i][1], acc[i][2], acc[i][3]);
                *(float4*)(rowp + 4) = make_float4(acc[i][4], acc[i][5], acc[i][6], acc[i][7]);
            }
        }
        __syncthreads();
        if (wv < half) {
            float* tb = &smem[wv * TILE_F];
#pragma unroll
            for (int i = 0; i < 8; ++i) {
                float* rowp = &tb[(8 * tr + i) * TSTR + 8 * ec];
                float4 a = *(const float4*)rowp;
                float4 b = *(const float4*)(rowp + 4);
                acc[i][0] += a.x; acc[i][1] += a.y; acc[i][2] += a.z; acc[i][3] += a.w;
                acc[i][4] += b.x; acc[i][5] += b.y; acc[i][6] += b.z; acc[i][7] += b.w;
            }
        }
        __syncthreads();
    }

    // ---- epilogue: wave 0 holds the final 64x64 tile ----
    if (wv == 0) {
        const size_t offSel = (size_t)nTok * 2;
        const size_t offLog = (size_t)nTok * 4;

        float4 b0 = *(const float4*)(Bv + 8 * ec);
        float4 b1 = *(const float4*)(Bv + 8 * ec + 4);
#pragma unroll
        for (int i = 0; i < 8; ++i) {
            acc[i][0] += b0.x; acc[i][1] += b0.y; acc[i][2] += b0.z; acc[i][3] += b0.w;
            acc[i][4] += b1.x; acc[i][5] += b1.y; acc[i][6] += b1.z; acc[i][7] += b1.w;
        }
        // router_logits: coalesced 16B stores, lanes of a tr-group cover a row
#pragma unroll
        for (int i = 0; i < 8; ++i) {
            float* dst = out + offLog + (size_t)(t0 + 8 * tr + i) * NEXP + 8 * ec;
            *(float4*)dst       = make_float4(acc[i][0], acc[i][1], acc[i][2], acc[i][3]);
            *(float4*)(dst + 4) = make_float4(acc[i][4], acc[i][5], acc[i][6], acc[i][7]);
        }
        // top-2: per-lane scan of its 8 experts, then 3-step shfl_xor merge
        // across the 8 ec-lanes. Ties -> lowest expert index (jax top_k).
#pragma unroll
        for (int i = 0; i < 8; ++i) {
            float m1 = acc[i][0]; int i1 = 8 * ec;
            float m2 = -INFINITY; int i2 = 0;
#pragma unroll
            for (int j = 1; j < 8; ++j) {
                const float v = acc[i][j]; const int e = 8 * ec + j;
                if (v > m1)      { m2 = m1; i2 = i1; m1 = v; i1 = e; }
                else if (v > m2) { m2 = v; i2 = e; }
            }
#pragma unroll
            for (int m = 1; m < 8; m <<= 1) {
                const float om1 = __shfl_xor(m1, m);
                const int   oi1 = __shfl_xor(i1, m);
                const float om2 = __shfl_xor(m2, m);
                const int   oi2 = __shfl_xor(i2, m);
                const bool b1 = (om1 > m1) || (om1 == m1 && oi1 < i1);
                const float n1  = b1 ? om1 : m1; const int ni1 = b1 ? oi1 : i1;
                const float c2v = b1 ? m1 : om1; const int c2i = b1 ? i1 : oi1;
                const float c3v = b1 ? om2 : m2; const int c3i = b1 ? oi2 : i2;
                const bool b2 = (c3v > c2v) || (c3v == c2v && c3i < c2i);
                m1 = n1; i1 = ni1;
                m2 = b2 ? c3v : c2v; i2 = b2 ? c3i : c2i;
            }
            if (ec == 0) {
                const float ex  = expf(m2 - m1);
                const float inv = 1.0f / (1.0f + ex);
                const int t = t0 + 8 * tr + i;
                *(float2*)(out + (size_t)t * 2)          = make_float2(inv, ex * inv);
                *(float2*)(out + offSel + (size_t)t * 2) = make_float2((float)i1, (float)i2);
            }
        }
        if (blockIdx.x == 0 && tid == 0)
            out[offLog + (size_t)nTok * NEXP] = 0.0f;   // aux_loss
    }
}

extern "C" void kernel_launch(void* const* d_in, const int* in_sizes, int n_in,
                              void* d_out, int out_size, void* d_ws, size_t ws_size,
                              hipStream_t stream)
{
    const float* X  = (const float*)d_in[0];
    const float* W  = (const float*)d_in[1];
    const float* Bv = (const float*)d_in[2];
    float* out = (float*)d_out;
    const int nTok   = in_sizes[0] / HIDDEN;   // 16384
    const int blocks = nTok / TOKS;            // 256
    router_kernel<<<blocks, 512, 0, stream>>>(X, W, Bv, out, nTok);
}